// Round 3
// baseline (186.763 us; speedup 1.0000x reference)
//
#include <hip/hip_runtime.h>

#define D_DIM 1024
#define B_HALF 4096
#define NROWS 8192
#define INV_TEMP 10.0f
#define NT 32     // 8192 / 256 tiles per side
#define NKT 32    // 1024 / 32 K-tiles

typedef __bf16 bf16x8 __attribute__((ext_vector_type(8)));
typedef float floatx4 __attribute__((ext_vector_type(4)));

#define MFMA16 __builtin_amdgcn_mfma_f32_16x16x32_bf16

__device__ __forceinline__ unsigned short f32_to_bf16(float f) {
    union { float f; unsigned u; } v; v.f = f;
    unsigned r = 0x7FFFu + ((v.u >> 16) & 1u);
    return (unsigned short)((v.u + r) >> 16);
}

// Kernel 1: L2-normalize rows of z1,z2 -> bf16 R [8192][1024]
__global__ __launch_bounds__(256) void normalize_kernel(
    const float* __restrict__ z1, const float* __restrict__ z2,
    unsigned short* __restrict__ R)
{
    const int row = blockIdx.x;
    const int tid = threadIdx.x;
    const float* src = (row < B_HALF) ? (z1 + (size_t)row * D_DIM)
                                      : (z2 + (size_t)(row - B_HALF) * D_DIM);
    float4 v = ((const float4*)src)[tid];
    float ss = v.x * v.x + v.y * v.y + v.z * v.z + v.w * v.w;
    #pragma unroll
    for (int off = 32; off > 0; off >>= 1) ss += __shfl_down(ss, off);
    __shared__ float wsum[4];
    if ((tid & 63) == 0) wsum[tid >> 6] = ss;
    __syncthreads();
    float tot = wsum[0] + wsum[1] + wsum[2] + wsum[3];
    float scale = 1.0f / fmaxf(sqrtf(tot), 1e-12f);
    ushort4 o;
    o.x = f32_to_bf16(v.x * scale);
    o.y = f32_to_bf16(v.y * scale);
    o.z = f32_to_bf16(v.z * scale);
    o.w = f32_to_bf16(v.w * scale);
    ((ushort4*)(R + (size_t)row * D_DIM))[tid] = o;
}

// Kernel 2: 256x256 tiles, upper-tri (rt <= ct). 8 waves (2Mx4N), BK=32,
// double-buffered 64 KiB LDS -> 2 blocks/CU co-resident (m114 overlap).
// Single barrier + single vmcnt(0) per K-tile. XOR-swizzled LDS (slot ^=
// (row>>1)&3) via pre-swizzled global source; ds_read_b128 2-way max (free).
__global__ __launch_bounds__(512, 2) void gemm_lse_kernel(
    const unsigned short* __restrict__ R,
    float* __restrict__ partial, float* __restrict__ pos)
{
    __shared__ unsigned short lds[2][2][256 * 32];   // [buf][A/B][row*32+col] = 64 KiB

    // decode linear block id -> (rt, ct), rt <= ct
    int t = blockIdx.x;
    int rt = 0;
    while (t >= NT - rt) { t -= NT - rt; ++rt; }
    const int ct = rt + t;
    const bool isDiag = (rt == ct);

    const int tid = threadIdx.x;
    const int wave = tid >> 6, lane = tid & 63;
    const int wm = wave >> 2, wn = wave & 3;         // 2 x 4 wave grid
    const int row0 = rt * 256, col0 = ct * 256;
    const int lm = lane & 15, lq = lane >> 4;

    const unsigned short* __restrict__ gA = R + (size_t)row0 * D_DIM;
    const unsigned short* __restrict__ gB = R + (size_t)col0 * D_DIM;

    // staging: one global_load_lds issue = 64 lanes x 16B = 16 rows x 4 slots.
    // lane l -> row (l>>2), LDS slot (l&3) [linear dest]. Pre-swizzle the
    // GLOBAL slot: s_g = (l&3) ^ ((row>>1)&3)  (involution; read same XOR).
    const int sRow = lane >> 2;                       // 0..15
    const int sCol = (lane & 3) ^ ((sRow >> 1) & 3);  // swizzled 16B slot
    // ds_read swizzled k-slot: row bits1-2 == lm bits1-2 for all frags
    const int sk = ((lq ^ ((lm >> 1) & 3)) * 8);
    const int aBase = (wm * 128 + lm) * 32 + sk;
    const int bBase = (wn * 64 + lm) * 32 + sk;

    floatx4 acc[8][4] = {};                           // 128 accumulators

#define STAGE(dstbuf, kk) \
    { _Pragma("unroll") \
      for (int i = 0; i < 2; ++i) { \
        __builtin_amdgcn_global_load_lds( \
          (const __attribute__((address_space(1))) unsigned int*)(gA + (size_t)(wave * 32 + i * 16 + sRow) * D_DIM + (kk) + sCol * 8), \
          (__attribute__((address_space(3))) unsigned int*)(&lds[dstbuf][0][(wave * 32 + i * 16) * 32]), \
          16, 0, 0); \
        __builtin_amdgcn_global_load_lds( \
          (const __attribute__((address_space(1))) unsigned int*)(gB + (size_t)(wave * 32 + i * 16 + sRow) * D_DIM + (kk) + sCol * 8), \
          (__attribute__((address_space(3))) unsigned int*)(&lds[dstbuf][1][(wave * 32 + i * 16) * 32]), \
          16, 0, 0); \
      } }

    // prologue: stage K-tile 0 into buf 0
    STAGE(0, 0)
    asm volatile("s_waitcnt vmcnt(0)" ::: "memory");
    __builtin_amdgcn_s_barrier();

    for (int kt = 0; kt < NKT; ++kt) {
        const int buf = kt & 1;
        const unsigned short* As = &lds[buf][0][0];
        const unsigned short* Bs = &lds[buf][1][0];

        if (kt + 1 < NKT) STAGE(buf ^ 1, (kt + 1) * 32)

        bf16x8 af[8], bf[4];
        #pragma unroll
        for (int mi = 0; mi < 8; ++mi)
            af[mi] = *(const bf16x8*)(As + aBase + mi * 512);
        #pragma unroll
        for (int ni = 0; ni < 4; ++ni)
            bf[ni] = *(const bf16x8*)(Bs + bBase + ni * 512);

        __builtin_amdgcn_s_setprio(1);
        #pragma unroll
        for (int mi = 0; mi < 8; ++mi)
            #pragma unroll
            for (int ni = 0; ni < 4; ++ni)
                acc[mi][ni] = MFMA16(af[mi], bf[ni], acc[mi][ni], 0, 0, 0);
        __builtin_amdgcn_s_setprio(0);

        asm volatile("s_waitcnt vmcnt(0)" ::: "memory");
        __builtin_amdgcn_s_barrier();
    }

    // Epilogue: staging LDS is dead past the final barrier -> overlay sums.
    float* rowsum = (float*)&lds[0][0][0];   // [4][256]
    float* colsum = rowsum + 4 * 256;        // [2][256]

    float ecol[4] = {0.0f, 0.0f, 0.0f, 0.0f};
    #pragma unroll
    for (int mi = 0; mi < 8; ++mi) {
        #pragma unroll
        for (int reg = 0; reg < 4; ++reg) {
            const int gr = row0 + wm * 128 + mi * 16 + lq * 4 + reg;
            float esum = 0.0f;
            #pragma unroll
            for (int ni = 0; ni < 4; ++ni) {
                const int gc = col0 + wn * 64 + ni * 16 + lm;
                float s = acc[mi][ni][reg] * INV_TEMP;
                if (gc == gr + B_HALF) { pos[gr] = s; pos[gc] = s; }
                float e = (gc == gr) ? 0.0f : __expf(s);
                esum += e;
                ecol[ni] += e;
            }
            esum += __shfl_xor(esum, 1);
            esum += __shfl_xor(esum, 2);
            esum += __shfl_xor(esum, 4);
            esum += __shfl_xor(esum, 8);
            if (lm == 0) rowsum[wn * 256 + wm * 128 + mi * 16 + lq * 4 + reg] = esum;
        }
    }
    #pragma unroll
    for (int ni = 0; ni < 4; ++ni) {
        ecol[ni] += __shfl_xor(ecol[ni], 16);
        ecol[ni] += __shfl_xor(ecol[ni], 32);
    }
    if (lq == 0 && !isDiag) {
        #pragma unroll
        for (int ni = 0; ni < 4; ++ni)
            colsum[wm * 256 + wn * 64 + ni * 16 + lm] = ecol[ni];
    }
    __syncthreads();
    if (tid < 256) {
        float rs = rowsum[0 * 256 + tid] + rowsum[1 * 256 + tid]
                 + rowsum[2 * 256 + tid] + rowsum[3 * 256 + tid];
        partial[(size_t)(row0 + tid) * NT + ct] = rs;
        if (!isDiag) {
            float cs = colsum[0 * 256 + tid] + colsum[1 * 256 + tid];
            partial[(size_t)(col0 + tid) * NT + rt] = cs;
        }
    }
}

// Kernel 3: S_r = sum of 32 partials; loss = mean(log1p(S * exp(-pos)))
__global__ __launch_bounds__(256) void finalize_kernel(
    const float* __restrict__ partial, const float* __restrict__ pos,
    float* __restrict__ out)
{
    const int r = blockIdx.x * 256 + threadIdx.x;
    const float4* p = (const float4*)(partial + (size_t)r * NT);
    float S = 0.0f;
    #pragma unroll
    for (int i = 0; i < 8; ++i) { float4 v = p[i]; S += (v.x + v.y) + (v.z + v.w); }
    const float po = pos[r];
    float contrib = log1pf(S * __expf(-po));
    #pragma unroll
    for (int off = 32; off > 0; off >>= 1) contrib += __shfl_down(contrib, off);
    __shared__ float wsum[4];
    if ((threadIdx.x & 63) == 0) wsum[threadIdx.x >> 6] = contrib;
    __syncthreads();
    if (threadIdx.x == 0)
        atomicAdd(out, (wsum[0] + wsum[1] + wsum[2] + wsum[3]) * (1.0f / 8192.0f));
}

extern "C" void kernel_launch(void* const* d_in, const int* in_sizes, int n_in,
                              void* d_out, int out_size, void* d_ws, size_t ws_size,
                              hipStream_t stream)
{
    const float* z1 = (const float*)d_in[0];
    const float* z2 = (const float*)d_in[1];
    float* out = (float*)d_out;
    char* ws = (char*)d_ws;
    unsigned short* R = (unsigned short*)ws;                      // 16 MiB bf16 reps
    float* partial = (float*)(ws + (size_t)16 * 1024 * 1024);     // 1 MiB [8192][32]
    float* pos     = (float*)(ws + (size_t)18 * 1024 * 1024);     // 32 KiB [8192]

    hipMemsetAsync(d_out, 0, sizeof(float), stream);
    normalize_kernel<<<NROWS, 256, 0, stream>>>(z1, z2, R);
    gemm_lse_kernel<<<528, 512, 0, stream>>>(R, partial, pos);    // 32*33/2 upper-tri tiles
    finalize_kernel<<<32, 256, 0, stream>>>(partial, pos, out);
}

// Round 5
// 180.933 us; speedup vs baseline: 1.0322x; 1.0322x over previous
//
#include <hip/hip_runtime.h>

#define D_DIM 1024
#define B_HALF 4096
#define NROWS 8192
#define INV_TEMP 10.0f
#define NT 32     // 8192 / 256 tiles per side
#define NKT 16    // 1024 / 64 K-tiles

typedef __bf16 bf16x8 __attribute__((ext_vector_type(8)));
typedef float floatx4 __attribute__((ext_vector_type(4)));

#define MFMA16 __builtin_amdgcn_mfma_f32_16x16x32_bf16

__device__ __forceinline__ unsigned short f32_to_bf16(float f) {
    union { float f; unsigned u; } v; v.f = f;
    unsigned r = 0x7FFFu + ((v.u >> 16) & 1u);
    return (unsigned short)((v.u + r) >> 16);
}

// Kernel 1: L2-normalize rows of z1,z2 -> bf16 R [8192][1024]
__global__ __launch_bounds__(256) void normalize_kernel(
    const float* __restrict__ z1, const float* __restrict__ z2,
    unsigned short* __restrict__ R)
{
    const int row = blockIdx.x;
    const int tid = threadIdx.x;
    const float* src = (row < B_HALF) ? (z1 + (size_t)row * D_DIM)
                                      : (z2 + (size_t)(row - B_HALF) * D_DIM);
    float4 v = ((const float4*)src)[tid];
    float ss = v.x * v.x + v.y * v.y + v.z * v.z + v.w * v.w;
    #pragma unroll
    for (int off = 32; off > 0; off >>= 1) ss += __shfl_down(ss, off);
    __shared__ float wsum[4];
    if ((tid & 63) == 0) wsum[tid >> 6] = ss;
    __syncthreads();
    float tot = wsum[0] + wsum[1] + wsum[2] + wsum[3];
    float scale = 1.0f / fmaxf(sqrtf(tot), 1e-12f);
    ushort4 o;
    o.x = f32_to_bf16(v.x * scale);
    o.y = f32_to_bf16(v.y * scale);
    o.z = f32_to_bf16(v.z * scale);
    o.w = f32_to_bf16(v.w * scale);
    ((ushort4*)(R + (size_t)row * D_DIM))[tid] = o;
}

// Kernel 2: 256x256 upper-tri tiles, 8 waves (2Mx4N), BK=64, m201-style
// 4-phase schedule with COUNTED vmcnt (never 0 in steady loop):
//   stage order per tile: A-lo(ph1), B-lo(ph2), B-hi(ph3), A-hi(ph4)
//   drains: vmcnt(4) @ph2-end (frees prev A-hi), vmcnt(2) @ph4-end
//           (frees next A-lo/B-lo/B-hi), each BEFORE the phase barrier.
// Wave output = 2 row-strips x 2 col-strips (one per staged half) so every
// phase's operands are drain-guaranteed for ALL waves. XOR slot-swizzle
// (slot ^= row&7) via pre-swizzled global source keeps ds_read_b128 2-way.
__global__ __launch_bounds__(512, 2) void gemm_lse_kernel(
    const unsigned short* __restrict__ R,
    float* __restrict__ partial, float* __restrict__ pos)
{
    __shared__ unsigned short lds[2][2][256 * 64];   // [buf][A/B][row*64+slot8] 128 KiB

    // XCD-aware swizzle (bijective: 528 = 8*66), then decode (rt,ct), rt<=ct
    int t = blockIdx.x;
    t = (t & 7) * 66 + (t >> 3);
    int rt = 0;
    while (t >= NT - rt) { t -= NT - rt; ++rt; }
    const int ct = rt + t;
    const bool isDiag = (rt == ct);

    const int tid = threadIdx.x;
    const int wave = tid >> 6, lane = tid & 63;
    const int wm = wave >> 2, wn = wave & 3;         // 2 x 4 wave grid
    const int row0 = rt * 256, col0 = ct * 256;
    const int lm = lane & 15, lq = lane >> 4;

    const unsigned short* __restrict__ gA = R + (size_t)row0 * D_DIM;
    const unsigned short* __restrict__ gB = R + (size_t)col0 * D_DIM;

    // staging: one issue = 64 lanes x 16B = 8 rows x 8 slots (1 KB), linear
    // LDS dest. Global slot pre-swizzled: s_g = (l&7) ^ (l>>3)  (row&7).
    const int sR8 = lane >> 3;            // 0..7 (row within 8-row group)
    const int sS8 = (lane & 7) ^ sR8;     // swizzled global 16B slot
    // ds_read swizzled k-slots (row&7 == lm&7 for all frag rows)
    const int sk0 = ((0 + lq) ^ (lm & 7)) * 8;
    const int sk1 = ((4 + lq) ^ (lm & 7)) * 8;
    const int aOff = (wm * 64 + lm) * 64;   // A row-strip base (elems)
    const int bOff = (wn * 32 + lm) * 64;   // B col-strip base (elems)

    floatx4 acc[8][4] = {};                 // [mi(strip|frag)][ni] 128 regs

#define STAGE_HALF(d, m, h, kk) \
    { _Pragma("unroll") for (int i = 0; i < 2; ++i) { \
        __builtin_amdgcn_global_load_lds( \
          (const __attribute__((address_space(1))) unsigned int*)( \
            ((m) ? gB : gA) + (size_t)((h) * 128 + wave * 16 + i * 8 + sR8) * D_DIM + (kk) + sS8 * 8), \
          (__attribute__((address_space(3))) unsigned int*)( \
            &lds[d][m][((h) * 128 + wave * 16 + i * 8) * 64]), \
          16, 0, 0); } }

    // prologue: stage tile 0 in FIFO order A-lo, B-lo, B-hi, A-hi
    STAGE_HALF(0, 0, 0, 0)
    STAGE_HALF(0, 1, 0, 0)
    STAGE_HALF(0, 1, 1, 0)
    STAGE_HALF(0, 0, 1, 0)
    asm volatile("s_waitcnt vmcnt(2)" ::: "memory");   // A-lo,B-lo,B-hi landed
    __builtin_amdgcn_s_barrier();

    bf16x8 aF[4][2];       // current A half-strip frags [mi][ksub]
    bf16x8 bF[2][2][2];    // both B col-strip halves [nh][ni][ksub]

    for (int kt = 0; kt < NKT; ++kt) {
        const int buf = kt & 1;
        const unsigned short* As = &lds[buf][0][0];
        const unsigned short* Bs = &lds[buf][1][0];
        const int kn = (kt + 1) * 64;
        const bool more = (kt + 1 < NKT);

        // ---- phase 1: read A-lo + B-lo; stage next A-lo; MFMA (mi0-3, ni0-1)
        #pragma unroll
        for (int mi = 0; mi < 4; ++mi) {
            aF[mi][0] = *(const bf16x8*)(As + aOff + mi * 1024 + sk0);
            aF[mi][1] = *(const bf16x8*)(As + aOff + mi * 1024 + sk1);
        }
        #pragma unroll
        for (int ni = 0; ni < 2; ++ni) {
            bF[0][ni][0] = *(const bf16x8*)(Bs + bOff + ni * 1024 + sk0);
            bF[0][ni][1] = *(const bf16x8*)(Bs + bOff + ni * 1024 + sk1);
        }
        if (more) STAGE_HALF(buf ^ 1, 0, 0, kn)
        __builtin_amdgcn_s_barrier();
        __builtin_amdgcn_s_setprio(1);
        #pragma unroll
        for (int mi = 0; mi < 4; ++mi)
            #pragma unroll
            for (int ni = 0; ni < 2; ++ni) {
                acc[mi][ni] = MFMA16(aF[mi][0], bF[0][ni][0], acc[mi][ni], 0, 0, 0);
                acc[mi][ni] = MFMA16(aF[mi][1], bF[0][ni][1], acc[mi][ni], 0, 0, 0);
            }
        __builtin_amdgcn_s_setprio(0);
        __builtin_amdgcn_s_barrier();

        // ---- phase 2: read B-hi; stage next B-lo; MFMA (mi0-3, ni2-3)
        #pragma unroll
        for (int ni = 0; ni < 2; ++ni) {
            bF[1][ni][0] = *(const bf16x8*)(Bs + bOff + 8192 + ni * 1024 + sk0);
            bF[1][ni][1] = *(const bf16x8*)(Bs + bOff + 8192 + ni * 1024 + sk1);
        }
        if (more) STAGE_HALF(buf ^ 1, 1, 0, kn)
        __builtin_amdgcn_s_barrier();
        __builtin_amdgcn_s_setprio(1);
        #pragma unroll
        for (int mi = 0; mi < 4; ++mi)
            #pragma unroll
            for (int ni = 0; ni < 2; ++ni) {
                acc[mi][2 + ni] = MFMA16(aF[mi][0], bF[1][ni][0], acc[mi][2 + ni], 0, 0, 0);
                acc[mi][2 + ni] = MFMA16(aF[mi][1], bF[1][ni][1], acc[mi][2 + ni], 0, 0, 0);
            }
        __builtin_amdgcn_s_setprio(0);
        if (more) { asm volatile("s_waitcnt vmcnt(4)" ::: "memory"); }   // prev A-hi landed
        else      { asm volatile("s_waitcnt vmcnt(0)" ::: "memory"); }
        __builtin_amdgcn_s_barrier();

        // ---- phase 3: read A-hi; stage next B-hi; MFMA (mi4-7, ni0-1)
        #pragma unroll
        for (int mi = 0; mi < 4; ++mi) {
            aF[mi][0] = *(const bf16x8*)(As + aOff + 8192 + mi * 1024 + sk0);
            aF[mi][1] = *(const bf16x8*)(As + aOff + 8192 + mi * 1024 + sk1);
        }
        if (more) STAGE_HALF(buf ^ 1, 1, 1, kn)
        __builtin_amdgcn_s_barrier();
        __builtin_amdgcn_s_setprio(1);
        #pragma unroll
        for (int mi = 0; mi < 4; ++mi)
            #pragma unroll
            for (int ni = 0; ni < 2; ++ni) {
                acc[4 + mi][ni] = MFMA16(aF[mi][0], bF[0][ni][0], acc[4 + mi][ni], 0, 0, 0);
                acc[4 + mi][ni] = MFMA16(aF[mi][1], bF[0][ni][1], acc[4 + mi][ni], 0, 0, 0);
            }
        __builtin_amdgcn_s_setprio(0);
        __builtin_amdgcn_s_barrier();

        // ---- phase 4: stage next A-hi; MFMA (mi4-7, ni2-3); counted drain
        if (more) STAGE_HALF(buf ^ 1, 0, 1, kn)
        __builtin_amdgcn_s_setprio(1);
        #pragma unroll
        for (int mi = 0; mi < 4; ++mi)
            #pragma unroll
            for (int ni = 0; ni < 2; ++ni) {
                acc[4 + mi][2 + ni] = MFMA16(aF[mi][0], bF[1][ni][0], acc[4 + mi][2 + ni], 0, 0, 0);
                acc[4 + mi][2 + ni] = MFMA16(aF[mi][1], bF[1][ni][1], acc[4 + mi][2 + ni], 0, 0, 0);
            }
        __builtin_amdgcn_s_setprio(0);
        asm volatile("s_waitcnt vmcnt(2)" ::: "memory");   // next A-lo,B-lo,B-hi landed
        __builtin_amdgcn_s_barrier();
    }

    // Epilogue: staging LDS dead -> overlay sums.
    float* rowsum = (float*)&lds[0][0][0];   // [4][256]
    float* colsum = rowsum + 4 * 256;        // [2][256]

    float ecol[4] = {0.0f, 0.0f, 0.0f, 0.0f};
    #pragma unroll
    for (int mi = 0; mi < 8; ++mi) {
        const int rloc = (mi >> 2) * 128 + wm * 64 + (mi & 3) * 16 + lq * 4;
        #pragma unroll
        for (int reg = 0; reg < 4; ++reg) {
            const int gr = row0 + rloc + reg;
            float esum = 0.0f;
            #pragma unroll
            for (int ni = 0; ni < 4; ++ni) {
                const int gc = col0 + (ni >> 1) * 128 + wn * 32 + (ni & 1) * 16 + lm;
                float s = acc[mi][ni][reg] * INV_TEMP;
                if (gc == gr + B_HALF) { pos[gr] = s; pos[gc] = s; }
                float e = (gc == gr) ? 0.0f : __expf(s);
                esum += e;
                ecol[ni] += e;
            }
            esum += __shfl_xor(esum, 1);
            esum += __shfl_xor(esum, 2);
            esum += __shfl_xor(esum, 4);
            esum += __shfl_xor(esum, 8);
            if (lm == 0) rowsum[wn * 256 + rloc + reg] = esum;
        }
    }
    #pragma unroll
    for (int ni = 0; ni < 4; ++ni) {
        ecol[ni] += __shfl_xor(ecol[ni], 16);
        ecol[ni] += __shfl_xor(ecol[ni], 32);
    }
    if (lq == 0 && !isDiag) {
        #pragma unroll
        for (int ni = 0; ni < 4; ++ni)
            colsum[wm * 256 + (ni >> 1) * 128 + wn * 32 + (ni & 1) * 16 + lm] = ecol[ni];
    }
    __syncthreads();
    if (tid < 256) {
        float rs = rowsum[0 * 256 + tid] + rowsum[1 * 256 + tid]
                 + rowsum[2 * 256 + tid] + rowsum[3 * 256 + tid];
        partial[(size_t)(row0 + tid) * NT + ct] = rs;
        if (!isDiag) {
            float cs = colsum[0 * 256 + tid] + colsum[1 * 256 + tid];
            partial[(size_t)(col0 + tid) * NT + rt] = cs;
        }
    }
}

// Kernel 3: S_r = sum of 32 partials; loss = mean(log1p(S * exp(-pos)))
__global__ __launch_bounds__(256) void finalize_kernel(
    const float* __restrict__ partial, const float* __restrict__ pos,
    float* __restrict__ out)
{
    const int r = blockIdx.x * 256 + threadIdx.x;
    const float4* p = (const float4*)(partial + (size_t)r * NT);
    float S = 0.0f;
    #pragma unroll
    for (int i = 0; i < 8; ++i) { float4 v = p[i]; S += (v.x + v.y) + (v.z + v.w); }
    const float po = pos[r];
    float contrib = log1pf(S * __expf(-po));
    #pragma unroll
    for (int off = 32; off > 0; off >>= 1) contrib += __shfl_down(contrib, off);
    __shared__ float wsum[4];
    if ((threadIdx.x & 63) == 0) wsum[threadIdx.x >> 6] = contrib;
    __syncthreads();
    if (threadIdx.x == 0)
        atomicAdd(out, (wsum[0] + wsum[1] + wsum[2] + wsum[3]) * (1.0f / 8192.0f));
}

extern "C" void kernel_launch(void* const* d_in, const int* in_sizes, int n_in,
                              void* d_out, int out_size, void* d_ws, size_t ws_size,
                              hipStream_t stream)
{
    const float* z1 = (const float*)d_in[0];
    const float* z2 = (const float*)d_in[1];
    float* out = (float*)d_out;
    char* ws = (char*)d_ws;
    unsigned short* R = (unsigned short*)ws;                      // 16 MiB bf16 reps
    float* partial = (float*)(ws + (size_t)16 * 1024 * 1024);     // 1 MiB [8192][32]
    float* pos     = (float*)(ws + (size_t)18 * 1024 * 1024);     // 32 KiB [8192]

    hipMemsetAsync(d_out, 0, sizeof(float), stream);
    normalize_kernel<<<NROWS, 256, 0, stream>>>(z1, z2, R);
    gemm_lse_kernel<<<528, 512, 0, stream>>>(R, partial, pos);    // 32*33/2 upper-tri tiles
    finalize_kernel<<<32, 256, 0, stream>>>(partial, pos, out);
}